// Round 1
// baseline (590.222 us; speedup 1.0000x reference)
//
#include <hip/hip_runtime.h>

// Problem constants (fixed shapes from setup_inputs)
#define B_ 4
#define T_ 512
#define C_ 8
#define F_ 257
#define TAPS 5
#define DELAY 3
#define N_ 40          // TAPS*C
#define NA 48          // N_ + C_ (augmented: R | P)
#define TP 505         // T - DELAY - TAPS + 1
#define T0 7           // DELAY + TAPS - 1
#define BF (B_*F_)     // 1028
#define BTCF ((size_t)B_*T_*C_*F_)
#define YS 514         // padded LDS row stride (float2) to break bank aliasing

// ---------------- K1: (B,T,C,F) planar re/im -> (B,F,C,T) interleaved float2
__global__ __launch_bounds__(256) void k_transpose_in(const float* __restrict__ in_re,
                                                      const float* __restrict__ in_im,
                                                      float2* __restrict__ Y) {
    __shared__ float2 tile[32][33];
    int ft = blockIdx.x % 9;     // f tile
    int tt = blockIdx.x / 9;     // t tile
    int c = blockIdx.y, b = blockIdx.z;
    int tx = threadIdx.x, ty = threadIdx.y;
    int f = ft * 32 + tx;
#pragma unroll
    for (int i = 0; i < 4; ++i) {
        int t = tt * 32 + ty + i * 8;
        if (f < F_) {
            size_t idx = ((size_t)(b * T_ + t) * C_ + c) * F_ + f;
            tile[ty + i * 8][tx] = make_float2(in_re[idx], in_im[idx]);
        }
    }
    __syncthreads();
    int t2 = tt * 32 + tx;
#pragma unroll
    for (int i = 0; i < 4; ++i) {
        int f2 = ft * 32 + ty + i * 8;
        if (f2 < F_) {
            Y[((size_t)(b * F_ + f2) * C_ + c) * T_ + t2] = tile[tx][ty + i * 8];
        }
    }
}

// ---------------- K2: power (B,F,T) = clamp(mean_c |Y|^2, 1e-6)
__global__ __launch_bounds__(256) void k_power(const float2* __restrict__ Y,
                                               float* __restrict__ pow_out) {
    int bf = blockIdx.x;
    const float2* Yp = Y + (size_t)bf * C_ * T_;
    for (int t = threadIdx.x; t < T_; t += 256) {
        float s = 0.f;
#pragma unroll
        for (int c = 0; c < C_; ++c) {
            float2 v = Yp[c * T_ + t];
            s += v.x * v.x + v.y * v.y;
        }
        s *= (1.0f / C_);
        s = fmaxf(s, 1e-6f);
        pow_out[(size_t)bf * T_ + t] = s;
    }
}

// ---------------- K3: build augmented [R | P] (40 x 48 complex double) per (b,f)
// R[j1,j2]  = sum_t invp[t+7] conj(Z[j1]) Z[j2],  Z[(k*8+d)] = Y[d, t+4-k]
// P[j , e]  = sum_t invp[t+7] conj(Z[j]) Y[e, t+7]
__global__ __launch_bounds__(256) void k_build(const float2* __restrict__ Y,
                                               const float* __restrict__ pow_in,
                                               double2* __restrict__ aug) {
    __shared__ float2 sY[C_ * YS];
    __shared__ double sInv[T_];
    int bf = blockIdx.x;
    int tid = threadIdx.x;
    const float2* Yp = Y + (size_t)bf * C_ * T_;
    for (int i = tid; i < C_ * T_; i += 256) {
        int c = i / T_, t = i - c * T_;
        sY[c * YS + t] = Yp[i];
    }
    for (int t = tid; t < T_; t += 256) {
        double p = (double)pow_in[(size_t)bf * T_ + t];
        sInv[t] = 1.0 / fmax(p, 1e-10);
    }
    __syncthreads();
    if (tid < 240) {
        int rg = tid / 12, cg = tid % 12;
        int r0 = rg * 2, c0 = cg * 4;
        int rowOff[2], colOff[4];
#pragma unroll
        for (int rr = 0; rr < 2; ++rr) {
            int j = r0 + rr;
            rowOff[rr] = (j & 7) * YS + (4 - (j >> 3));
        }
#pragma unroll
        for (int cc = 0; cc < 4; ++cc) {
            int j2 = c0 + cc;
            colOff[cc] = (j2 < N_) ? ((j2 & 7) * YS + (4 - (j2 >> 3)))
                                   : ((j2 - N_) * YS + T0);
        }
        double aRe[2][4] = {}, aIm[2][4] = {};
        for (int t = 0; t < TP; ++t) {
            double w = sInv[t + T0];
            double ra[2], rb[2];
#pragma unroll
            for (int rr = 0; rr < 2; ++rr) {
                float2 v = sY[rowOff[rr] + t];
                ra[rr] = w * (double)v.x;
                rb[rr] = w * (double)v.y;
            }
#pragma unroll
            for (int cc = 0; cc < 4; ++cc) {
                float2 v = sY[colOff[cc] + t];
                double cx = (double)v.x, cy = (double)v.y;
#pragma unroll
                for (int rr = 0; rr < 2; ++rr) {
                    // (ra - i rb) * (cx + i cy)
                    aRe[rr][cc] += ra[rr] * cx + rb[rr] * cy;
                    aIm[rr][cc] += ra[rr] * cy - rb[rr] * cx;
                }
            }
        }
        double2* ap = aug + (size_t)bf * N_ * NA;
#pragma unroll
        for (int rr = 0; rr < 2; ++rr)
#pragma unroll
            for (int cc = 0; cc < 4; ++cc)
                ap[(r0 + rr) * NA + (c0 + cc)] = make_double2(aRe[rr][cc], aIm[rr][cc]);
    }
}

// ---------------- K4: per (b,f) solve (R + eps*tr/40*I) X = P via Gaussian elim (HPD, no pivot)
__global__ __launch_bounds__(256) void k_solve(const double2* __restrict__ aug_in,
                                               double2* __restrict__ G) {
    __shared__ double2 sA[N_ * NA];  // 30720 B
    int bf = blockIdx.x;
    int tid = threadIdx.x;
    const double2* ap = aug_in + (size_t)bf * N_ * NA;
    for (int i = tid; i < N_ * NA; i += 256) sA[i] = ap[i];
    __syncthreads();
    if (tid == 0) {
        double tr = 0;
        for (int j = 0; j < N_; ++j) tr += sA[j * NA + j].x;
        double ld = 1e-10 * tr / N_;
        for (int j = 0; j < N_; ++j) sA[j * NA + j].x += ld;
    }
    __syncthreads();
    // forward elimination (upper-triangularize); col p / row p untouched within step p
    for (int p = 0; p < N_ - 1; ++p) {
        double2 piv = sA[p * NA + p];
        double dnm = piv.x * piv.x + piv.y * piv.y;
        double pix = piv.x / dnm, piy = -piv.y / dnm;
        int nrows = N_ - 1 - p;
        int ncols = NA - 1 - p;
        int tot = nrows * ncols;
        for (int idx = tid; idx < tot; idx += 256) {
            int i = p + 1 + idx / ncols;
            int j = p + 1 + idx % ncols;
            double2 aip = sA[i * NA + p];
            double mx = aip.x * pix - aip.y * piy;
            double my = aip.x * piy + aip.y * pix;
            double2 apj = sA[p * NA + j];
            double2 v = sA[i * NA + j];
            v.x -= mx * apj.x - my * apj.y;
            v.y -= mx * apj.y + my * apj.x;
            sA[i * NA + j] = v;
        }
        __syncthreads();
    }
    // backward elimination on RHS columns (rows stay unscaled; scale at write-out)
    for (int p = N_ - 1; p > 0; --p) {
        double2 piv = sA[p * NA + p];
        double dnm = piv.x * piv.x + piv.y * piv.y;
        double pix = piv.x / dnm, piy = -piv.y / dnm;
        int tot = p * C_;
        for (int idx = tid; idx < tot; idx += 256) {
            int i = idx / C_;
            int c = idx - i * C_;
            double2 rhs = sA[p * NA + N_ + c];
            double xr = rhs.x * pix - rhs.y * piy;
            double xi = rhs.x * piy + rhs.y * pix;
            double2 aip = sA[i * NA + p];
            double2 v = sA[i * NA + N_ + c];
            v.x -= aip.x * xr - aip.y * xi;
            v.y -= aip.x * xi + aip.y * xr;
            sA[i * NA + N_ + c] = v;
        }
        __syncthreads();
    }
    // write G[j=(tau*8+d)][e] = RHS[j][e] / diag[j]
    double2* gp = G + (size_t)bf * N_ * C_;
    for (int idx = tid; idx < N_ * C_; idx += 256) {
        int j = idx / C_;
        int c = idx - j * C_;
        double2 piv = sA[j * NA + j];
        double dnm = piv.x * piv.x + piv.y * piv.y;
        double pix = piv.x / dnm, piy = -piv.y / dnm;
        double2 rhs = sA[j * NA + N_ + c];
        gp[idx] = make_double2(rhs.x * pix - rhs.y * piy, rhs.x * piy + rhs.y * pix);
    }
}

// ---------------- K5: enh[e,t] = Y[e,t] - sum_{tau,d} G[tau,d,e] Y[d, t-3-tau]; overwrite Y slab
__global__ __launch_bounds__(256) void k_tail(float2* __restrict__ Y,
                                              const double2* __restrict__ G) {
    __shared__ float2 sY[C_ * T_];
    __shared__ double2 sG[N_ * C_];
    int bf = blockIdx.x;
    int tid = threadIdx.x;
    float2* Yp = Y + (size_t)bf * C_ * T_;
    for (int i = tid; i < C_ * T_; i += 256) sY[i] = Yp[i];
    const double2* gp = G + (size_t)bf * N_ * C_;
    for (int i = tid; i < N_ * C_; i += 256) sG[i] = gp[i];
    __syncthreads();
    for (int idx = tid; idx < C_ * T_; idx += 256) {
        int e = idx / T_;
        int t = idx - e * T_;
        float2 cur = sY[e * T_ + t];
        double tr = 0, ti = 0;
        for (int tau = 0; tau < TAPS; ++tau) {
            int s = t - DELAY - tau;
            if (s < 0) break;  // larger tau => smaller s
#pragma unroll
            for (int d = 0; d < C_; ++d) {
                double2 g = sG[(tau * C_ + d) * C_ + e];
                float2 y = sY[d * T_ + s];
                tr += g.x * (double)y.x - g.y * (double)y.y;
                ti += g.x * (double)y.y + g.y * (double)y.x;
            }
        }
        Yp[idx] = make_float2((float)((double)cur.x - tr), (float)((double)cur.y - ti));
    }
}

// ---------------- K6: (B,F,C,T) float2 -> (B,T,C,F) planar re/im with ilens mask
__global__ __launch_bounds__(256) void k_transpose_out(const float2* __restrict__ Yenh,
                                                       const int* __restrict__ ilens,
                                                       float* __restrict__ out_re,
                                                       float* __restrict__ out_im) {
    __shared__ float2 tile[32][33];
    int ft = blockIdx.x % 9;
    int tt = blockIdx.x / 9;
    int c = blockIdx.y, b = blockIdx.z;
    int tx = threadIdx.x, ty = threadIdx.y;
    int ilen = ilens[b];
    int t = tt * 32 + tx;
#pragma unroll
    for (int i = 0; i < 4; ++i) {
        int f = ft * 32 + ty + i * 8;
        if (f < F_) tile[tx][ty + i * 8] = Yenh[((size_t)(b * F_ + f) * C_ + c) * T_ + t];
    }
    __syncthreads();
    int f2 = ft * 32 + tx;
#pragma unroll
    for (int i = 0; i < 4; ++i) {
        int t2 = tt * 32 + ty + i * 8;
        if (f2 < F_) {
            float2 v = tile[ty + i * 8][tx];
            if (t2 >= ilen) v = make_float2(0.f, 0.f);
            size_t o = ((size_t)(b * T_ + t2) * C_ + c) * F_ + f2;
            out_re[o] = v.x;
            out_im[o] = v.y;
        }
    }
}

extern "C" void kernel_launch(void* const* d_in, const int* in_sizes, int n_in,
                              void* d_out, int out_size, void* d_ws, size_t ws_size,
                              hipStream_t stream) {
    const float* in_re = (const float*)d_in[0];
    const float* in_im = (const float*)d_in[1];
    const int* ilens = (const int*)d_in[2];

    float* out_re = (float*)d_out;
    float* out_im = out_re + BTCF;
    float* out_pw = out_im + BTCF;   // (B,F,T) float32

    // workspace layout: Y float2 (33.7MB) | aug double2 (31.6MB) | G double2 (5.3MB) ~ 70.5MB
    char* ws = (char*)d_ws;
    float2* Y = (float2*)ws;
    size_t yBytes = (size_t)BF * C_ * T_ * sizeof(float2);
    double2* aug = (double2*)(ws + yBytes);
    size_t augBytes = (size_t)BF * N_ * NA * sizeof(double2);
    double2* G = (double2*)(ws + yBytes + augBytes);

    dim3 tb(32, 8);
    dim3 tg(9 * 16, C_, B_);   // 9 f-tiles x 16 t-tiles, C, B
    k_transpose_in<<<tg, tb, 0, stream>>>(in_re, in_im, Y);
    k_power<<<BF, 256, 0, stream>>>(Y, out_pw);
    k_build<<<BF, 256, 0, stream>>>(Y, out_pw, aug);
    k_solve<<<BF, 256, 0, stream>>>(aug, G);
    k_tail<<<BF, 256, 0, stream>>>(Y, G);
    k_transpose_out<<<tg, tb, 0, stream>>>(Y, ilens, out_re, out_im);
}